// Round 11
// baseline (236.946 us; speedup 1.0000x reference)
//
#include <hip/hip_runtime.h>
#include <math.h>

#define Bn 16
#define Cn 64
#define Hn 192
#define Wn 192
#define TH 8
#define TW 16
#define NPIX (Bn * Cn * Hn * Wn)           // 37748736
#define NBLK (Bn * (Hn / TH) * (Wn / TW))  // 4608
#define XT_BYTES (10 * 18 * 128)           // 23040 B: [row10][col18] x 128B (64ch bf16, 8 chunk-slots)

typedef short bf16x8 __attribute__((ext_vector_type(8)));
typedef float f32x4 __attribute__((ext_vector_type(4)));

// g_Ms[9 slices][64 rows][64 c] bf16, LINEAR (read straight to registers; 72 KB -> L2/L1-resident).
__device__ __align__(16) unsigned short g_Ms[9 * 64 * 64];
__device__ __align__(16) float g_b2[64];

static __device__ __forceinline__ unsigned short f2bf(float f) {
    union { float f; unsigned u; } x; x.f = f;
    unsigned r = x.u + 0x7fffu + ((x.u >> 16) & 1u);   // RNE
    return (unsigned short)(r >> 16);
}

__global__ void acdc_precompute(const float* __restrict__ cw, const float* __restrict__ A,
                                const float* __restrict__ D, const float* __restrict__ bias,
                                const int* __restrict__ perm) {
    __shared__ float mre[64];
    int p = blockIdx.x;      // output channel 0..63 (real row of the mix)
    int t = threadIdx.x;
    if (t < 64) {
        float re = 0.f;
        for (int k = 0; k < 64; ++k) {
            int a = (k * t) & 63;
            re += D[k] * cosf((float)a * 0.0981747704246810387f);  // pi/32
        }
        mre[t] = re;
    }
    __syncthreads();
    int pp = perm[p];
    for (int k0 = t; k0 < 576; k0 += 256) {
        int sp = k0 >> 6, c = k0 & 63;      // k = sp*64 + c
        int g = c >> 3, cil = c & 7;
        float val = 0.f;
        for (int o = 0; o < 8; ++o) {
            int oc = g * 8 + o;
            float gco = mre[(pp - oc + 64) & 63] * A[oc] * (0.125f / 64.0f);
            val += gco * cw[(oc * 8 + cil) * 9 + sp];
        }
        g_Ms[((sp * 64 + p) << 6) + c] = f2bf(val);
    }
    if (p == 0 && t < 64)
        g_b2[t] = bias[perm[t]] * 0.125f;
}

// (256,4): VGPR cap 128; est. ~95 live regs (acc 32 + A-frags 32 + B 16 + addr) — no spill.
// LDS 23 KB. Main loop is BARRIER-FREE: A-frags come straight from L1/L2-resident g_Ms.
__global__ __launch_bounds__(256, 4)
void acdc_main(const float* __restrict__ x, float* __restrict__ out) {
    __shared__ __align__(16) unsigned char xsb[XT_BYTES];

    int tid = threadIdx.x;
    // bijective XCD swizzle: NBLK % 8 == 0
    int bid = (blockIdx.x & 7) * (NBLK / 8) + (blockIdx.x >> 3);
    int bw = bid % 12, bh = (bid / 12) % 24, bb = bid / 288;
    int h0 = bh * TH, w0 = bw * TW;
    bool edge = (bh == 0) | (bh == 23) | (bw == 0) | (bw == 11);

    // ---- stage x window [10r][18c][64ch] -> bf16 LDS, chunk-swizzled ----
    const float* xb = x + (size_t)bb * Cn * Hn * Wn;
    #pragma unroll
    for (int k = 0; k < 8; ++k) {
        int idx = tid + (k << 8);
        if (idx >= 1920) break;
        int f = idx % 6;
        int rr = (idx / 6) % 10;
        int cp = idx / 60;                   // channel-pair 0..31
        int c0 = cp * 2;
        int gh = h0 + rr - 1;
        int gwf = w0 + f * 4 - 4;
        float v0[4], v1[4];
        const float* row0 = xb + ((size_t)c0 * Hn + gh) * Wn;
        const float* row1 = row0 + (size_t)(Hn * Wn);
        if (!edge) {                          // interior: block-uniform, all in-bounds
            float4 a = *(const float4*)(row0 + gwf);
            float4 b = *(const float4*)(row1 + gwf);
            v0[0]=a.x; v0[1]=a.y; v0[2]=a.z; v0[3]=a.w;
            v1[0]=b.x; v1[1]=b.y; v1[2]=b.z; v1[3]=b.w;
        } else {
            bool ghok = (unsigned)gh < (unsigned)Hn;
            if (ghok && gwf >= 0 && gwf <= Wn - 4) {
                float4 a = *(const float4*)(row0 + gwf);
                float4 b = *(const float4*)(row1 + gwf);
                v0[0]=a.x; v0[1]=a.y; v0[2]=a.z; v0[3]=a.w;
                v1[0]=b.x; v1[1]=b.y; v1[2]=b.z; v1[3]=b.w;
            } else {
                #pragma unroll
                for (int j = 0; j < 4; ++j) {
                    int gw = gwf + j;
                    bool ok = ghok && (unsigned)gw < (unsigned)Wn;
                    v0[j] = ok ? row0[gw] : 0.f;
                    v1[j] = ok ? row1[gw] : 0.f;
                }
            }
        }
        int chunk = cp >> 2;          // 0..7
        int sub = (cp & 3) * 4;
        #pragma unroll
        for (int j = 0; j < 4; ++j) {
            int col = f * 4 + j - 3;
            if ((unsigned)col >= 18u) continue;
            unsigned u;
            asm("v_cvt_pk_bf16_f32 %0, %1, %2" : "=v"(u) : "v"(v0[j]), "v"(v1[j]));
            int byte = (rr * 18 + col) * 128 + ((chunk ^ ((col + 3 * rr) & 7)) * 16) + sub;
            *(unsigned*)(xsb + byte) = u;
        }
    }
    __syncthreads();   // the ONLY barrier

    // ---- implicit GEMM: D[64 ch][128 px], barrier-free; A-frags from global (L1/L2) ----
    int lane = tid & 63;
    int wv = tid >> 6;        // wave -> pixel rows wv*2, wv*2+1
    int pxw = lane & 15;
    int q = lane >> 4;
    int rlane = lane & 15;
    int wv2 = wv * 2;

    // per-lane A base: row = rlane (+ m*16), col word = q*8 (+ kh*32)
    const unsigned char* mp = (const unsigned char*)g_Ms + (rlane << 7) + (q << 4);

    f32x4 acc[4][2];
    #pragma unroll
    for (int m = 0; m < 4; ++m)
        #pragma unroll
        for (int nt = 0; nt < 2; ++nt)
            acc[m][nt] = (f32x4){0.f, 0.f, 0.f, 0.f};

    #pragma unroll
    for (int sp = 0; sp < 9; ++sp) {
        const int dy = sp / 3, dx = sp % 3;
        int col = pxw + dx;
        #pragma unroll
        for (int kh = 0; kh < 2; ++kh) {
            bf16x8 bfr[2];
            #pragma unroll
            for (int nt = 0; nt < 2; ++nt) {
                int row = wv2 + nt + dy;
                bfr[nt] = *(const bf16x8*)(xsb + (row * 18 + col) * 128 +
                            (((kh * 4 + q) ^ ((col + 3 * row) & 7)) * 16));
            }
            #pragma unroll
            for (int m = 0; m < 4; ++m) {
                bf16x8 am = *(const bf16x8*)(mp + sp * 8192 + m * 2048 + kh * 64);
                #pragma unroll
                for (int nt = 0; nt < 2; ++nt)
                    acc[m][nt] = __builtin_amdgcn_mfma_f32_16x16x32_bf16(
                        am, bfr[nt], acc[m][nt], 0, 0, 0);
            }
        }
    }

    // ---- epilogue: +bias, real-only coalesced stores ----
    #pragma unroll
    for (int m = 0; m < 4; ++m) {
        int rbase = m * 16 + q * 4;
        float4 bq = *(const float4*)(g_b2 + rbase);
        #pragma unroll
        for (int nt = 0; nt < 2; ++nt) {
            int hh = h0 + wv2 + nt;
            int ww = w0 + pxw;
            #pragma unroll
            for (int j = 0; j < 4; ++j) {
                int p = rbase + j;
                float bv = (j == 0) ? bq.x : (j == 1) ? bq.y : (j == 2) ? bq.z : bq.w;
                out[(((size_t)bb * Cn + p) * Hn + hh) * Wn + ww] = acc[m][nt][j] + bv;
            }
        }
    }
}

extern "C" void kernel_launch(void* const* d_in, const int* in_sizes, int n_in,
                              void* d_out, int out_size, void* d_ws, size_t ws_size,
                              hipStream_t stream) {
    const float* x    = (const float*)d_in[0];
    const float* cw   = (const float*)d_in[1];
    const float* A    = (const float*)d_in[2];
    const float* D    = (const float*)d_in[3];
    const float* bias = (const float*)d_in[4];
    const int*   perm = (const int*)d_in[5];

    acdc_precompute<<<dim3(64), dim3(256), 0, stream>>>(cw, A, D, bias, perm);
    acdc_main<<<dim3(NBLK), dim3(256), 0, stream>>>(x, (float*)d_out);
}

// Round 12
// 122.784 us; speedup vs baseline: 1.9298x; 1.9298x over previous
//
#include <hip/hip_runtime.h>
#include <math.h>

#define Bn 16
#define Cn 64
#define Hn 192
#define Wn 192
#define TH 8
#define TW 16
#define NPIX (Bn * Cn * Hn * Wn)           // 37748736
#define NBLK (Bn * (Hn / TH) * (Wn / TW))  // 4608
#define XT_BYTES (10 * 18 * 128)           // 23040 B: [row10][col18] x 128B (64ch bf16, 8 chunk-slots)

typedef short bf16x8 __attribute__((ext_vector_type(8)));
typedef float f32x4 __attribute__((ext_vector_type(4)));
typedef __attribute__((address_space(1))) const unsigned int as1_u32;
typedef __attribute__((address_space(3))) unsigned int as3_u32;

// g_Ms[9 slices][64 rows][64 c] bf16; within a row, c-octet g stored at slot (g ^ (row&7)).
__device__ __align__(16) unsigned short g_Ms[9 * 64 * 64];
__device__ __align__(16) float g_b2[64];

static __device__ __forceinline__ unsigned short f2bf(float f) {
    union { float f; unsigned u; } x; x.f = f;
    unsigned r = x.u + 0x7fffu + ((x.u >> 16) & 1u);   // RNE
    return (unsigned short)(r >> 16);
}

__global__ void acdc_precompute(const float* __restrict__ cw, const float* __restrict__ A,
                                const float* __restrict__ D, const float* __restrict__ bias,
                                const int* __restrict__ perm) {
    __shared__ float mre[64];
    int p = blockIdx.x;
    int t = threadIdx.x;
    if (t < 64) {
        float re = 0.f;
        for (int k = 0; k < 64; ++k) {
            int a = (k * t) & 63;
            re += D[k] * cosf((float)a * 0.0981747704246810387f);  // pi/32
        }
        mre[t] = re;
    }
    __syncthreads();
    int pp = perm[p];
    for (int k0 = t; k0 < 576; k0 += 256) {
        int sp = k0 >> 6, c = k0 & 63;
        int g = c >> 3, cil = c & 7;
        float val = 0.f;
        for (int o = 0; o < 8; ++o) {
            int oc = g * 8 + o;
            float gco = mre[(pp - oc + 64) & 63] * A[oc] * (0.125f / 64.0f);
            val += gco * cw[(oc * 8 + cil) * 9 + sp];
        }
        g_Ms[((sp * 64 + p) << 6) + (((g ^ (p & 7)) << 3) | cil)] = f2bf(val);
    }
    if (p == 0 && t < 64)
        g_b2[t] = bias[perm[t]] * 0.125f;
}

static __device__ __forceinline__ void stage_m(int sp, unsigned char* buf, int tid) {
    int lane = tid & 63, wv = tid >> 6;
    const unsigned char* src = (const unsigned char*)g_Ms + sp * 8192 + wv * 2048 + lane * 16;
    unsigned char* d = buf + wv * 2048;
    __builtin_amdgcn_global_load_lds((as1_u32*)(const void*)src,
                                     (as3_u32*)(void*)d, 16, 0, 0);
    __builtin_amdgcn_global_load_lds((as1_u32*)(const void*)(src + 1024),
                                     (as3_u32*)(void*)(d + 1024), 16, 0, 0);
}

struct PhaseCtx {
    const unsigned char* xsb;
    int pbase;    // (wv2*18 + pxw)*128
    int s0;       // pxw + 3*wv2
    int qh0, qh1; // q, q|4
    int aoff0, aoff1;  // rlane*128 + ((qh^(rlane&7))<<4)
};

template<int SP>
static __device__ __forceinline__ void do_phase(const PhaseCtx& c, const unsigned char* mb,
                                                f32x4 acc[4][2]) {
    constexpr int dy = SP / 3, dx = SP % 3;
    #pragma unroll
    for (int kh = 0; kh < 2; ++kh) {
        const int qh = kh ? c.qh1 : c.qh0;
        bf16x8 bfr[2];
        #pragma unroll
        for (int nt = 0; nt < 2; ++nt) {
            const int lin = ((nt + dy) * 18 + dx) * 128;           // compile-time
            int xr = (c.s0 + (dx + 3 * dy + 3 * nt)) & 7;          // 2 VALU
            bfr[nt] = *(const bf16x8*)(c.xsb + c.pbase + lin + ((qh ^ xr) << 4));
        }
        const unsigned char* ab = mb + (kh ? c.aoff1 : c.aoff0);
        bf16x8 am[4];
        #pragma unroll
        for (int m = 0; m < 4; ++m)
            am[m] = *(const bf16x8*)(ab + m * 2048);               // base + imm offset
        __builtin_amdgcn_s_setprio(1);
        #pragma unroll
        for (int m = 0; m < 4; ++m)
            #pragma unroll
            for (int nt = 0; nt < 2; ++nt)
                acc[m][nt] = __builtin_amdgcn_mfma_f32_16x16x32_bf16(
                    am[m], bfr[nt], acc[m][nt], 0, 0, 0);
        __builtin_amdgcn_s_setprio(0);
    }
}

template<int S0, int I>
static __device__ __forceinline__ void step(const PhaseCtx& c, unsigned char (*mbuf)[8192],
                                            f32x4 acc[4][2], int tid) {
    if constexpr (I < 8) stage_m((S0 + I + 1) % 9, mbuf[(I + 1) & 1], tid);
    do_phase<(S0 + I) % 9>(c, mbuf[I & 1], acc);
    __syncthreads();   // publishes stage(I+1) (vmcnt drained) + guards mbuf reuse
}

template<int S0>
static __device__ __forceinline__ void chain(const PhaseCtx& c, unsigned char (*mbuf)[8192],
                                             f32x4 acc[4][2], int tid) {
    step<S0, 0>(c, mbuf, acc, tid); step<S0, 1>(c, mbuf, acc, tid);
    step<S0, 2>(c, mbuf, acc, tid); step<S0, 3>(c, mbuf, acc, tid);
    step<S0, 4>(c, mbuf, acc, tid); step<S0, 5>(c, mbuf, acc, tid);
    step<S0, 6>(c, mbuf, acc, tid); step<S0, 7>(c, mbuf, acc, tid);
    step<S0, 8>(c, mbuf, acc, tid);
}

__global__ __launch_bounds__(256, 4)
void acdc_main(const float* __restrict__ x, float* __restrict__ out) {
    __shared__ __align__(16) unsigned char xsb[XT_BYTES];
    __shared__ __align__(16) unsigned char mbuf[2][8192];

    int tid = threadIdx.x;
    int bid = (blockIdx.x & 7) * (NBLK / 8) + (blockIdx.x >> 3);   // bijective XCD swizzle
    int bw = bid % 12, bh = (bid / 12) % 24, bb = bid / 288;
    int h0 = bh * TH, w0 = bw * TW;
    bool edge = (bh == 0) | (bh == 23) | (bw == 0) | (bw == 11);
    int ph = bid % 3;                       // phase stagger: rotation 0/3/6

    // ---- stage x window [10r][18c][64ch] -> bf16 LDS, chunk-swizzled ----
    const float* xb = x + (size_t)bb * Cn * Hn * Wn;
    int q60 = tid / 60, r60 = tid - q60 * 60;    // one division total
    #pragma unroll
    for (int k = 0; k < 8; ++k) {
        int r = r60 + (256 * k) % 60;            // compile-time constants after unroll
        int cp = q60 + (256 * k) / 60;
        if (r >= 60) { r -= 60; ++cp; }
        if (cp >= 32) break;
        int rr = (r * 171) >> 10;                // exact r/6 for r<60
        int f = r - rr * 6;
        int c0 = cp * 2;
        int gh = h0 + rr - 1;
        int gwf = w0 + f * 4 - 4;
        float v0[4], v1[4];
        const float* row0 = xb + ((size_t)c0 * Hn + gh) * Wn;
        const float* row1 = row0 + (size_t)(Hn * Wn);
        if (!edge) {
            float4 a = *(const float4*)(row0 + gwf);
            float4 b = *(const float4*)(row1 + gwf);
            v0[0]=a.x; v0[1]=a.y; v0[2]=a.z; v0[3]=a.w;
            v1[0]=b.x; v1[1]=b.y; v1[2]=b.z; v1[3]=b.w;
        } else {
            bool ghok = (unsigned)gh < (unsigned)Hn;
            if (ghok && gwf >= 0 && gwf <= Wn - 4) {
                float4 a = *(const float4*)(row0 + gwf);
                float4 b = *(const float4*)(row1 + gwf);
                v0[0]=a.x; v0[1]=a.y; v0[2]=a.z; v0[3]=a.w;
                v1[0]=b.x; v1[1]=b.y; v1[2]=b.z; v1[3]=b.w;
            } else {
                #pragma unroll
                for (int j = 0; j < 4; ++j) {
                    int gw = gwf + j;
                    bool ok = ghok && (unsigned)gw < (unsigned)Wn;
                    v0[j] = ok ? row0[gw] : 0.f;
                    v1[j] = ok ? row1[gw] : 0.f;
                }
            }
        }
        int chunk = cp >> 2;
        int sub = (cp & 3) * 4;
        #pragma unroll
        for (int j = 0; j < 4; ++j) {
            int col = f * 4 + j - 3;
            if ((unsigned)col >= 18u) continue;
            unsigned u;
            asm("v_cvt_pk_bf16_f32 %0, %1, %2" : "=v"(u) : "v"(v0[j]), "v"(v1[j]));
            int byte = (rr * 18 + col) * 128 + ((chunk ^ ((col + 3 * rr) & 7)) * 16) + sub;
            *(unsigned*)(xsb + byte) = u;
        }
    }
    stage_m(ph * 3, mbuf[0], tid);
    __syncthreads();

    // ---- implicit GEMM: 9 one-barrier phases, sp-rotated per block ----
    int lane = tid & 63;
    int wv = tid >> 6;
    int pxw = lane & 15;
    int q = lane >> 4;
    int rlane = lane & 15;
    int wv2 = wv * 2;

    PhaseCtx c;
    c.xsb = xsb;
    c.pbase = (wv2 * 18 + pxw) * 128;
    c.s0 = pxw + 3 * wv2;
    c.qh0 = q; c.qh1 = q | 4;
    c.aoff0 = rlane * 128 + ((c.qh0 ^ (rlane & 7)) << 4);
    c.aoff1 = rlane * 128 + ((c.qh1 ^ (rlane & 7)) << 4);

    f32x4 acc[4][2];
    #pragma unroll
    for (int m = 0; m < 4; ++m)
        #pragma unroll
        for (int nt = 0; nt < 2; ++nt)
            acc[m][nt] = (f32x4){0.f, 0.f, 0.f, 0.f};

    if (ph == 0)      chain<0>(c, mbuf, acc, tid);
    else if (ph == 1) chain<3>(c, mbuf, acc, tid);
    else              chain<6>(c, mbuf, acc, tid);

    // ---- epilogue: +bias, real-only coalesced stores ----
    #pragma unroll
    for (int m = 0; m < 4; ++m) {
        int rbase = m * 16 + q * 4;
        float4 bq = *(const float4*)(g_b2 + rbase);
        #pragma unroll
        for (int nt = 0; nt < 2; ++nt) {
            int hh = h0 + wv2 + nt;
            int ww = w0 + pxw;
            #pragma unroll
            for (int j = 0; j < 4; ++j) {
                int p = rbase + j;
                float bv = (j == 0) ? bq.x : (j == 1) ? bq.y : (j == 2) ? bq.z : bq.w;
                out[(((size_t)bb * Cn + p) * Hn + hh) * Wn + ww] = acc[m][nt][j] + bv;
            }
        }
    }
}

extern "C" void kernel_launch(void* const* d_in, const int* in_sizes, int n_in,
                              void* d_out, int out_size, void* d_ws, size_t ws_size,
                              hipStream_t stream) {
    const float* x    = (const float*)d_in[0];
    const float* cw   = (const float*)d_in[1];
    const float* A    = (const float*)d_in[2];
    const float* D    = (const float*)d_in[3];
    const float* bias = (const float*)d_in[4];
    const int*   perm = (const int*)d_in[5];

    acdc_precompute<<<dim3(64), dim3(256), 0, stream>>>(cw, A, D, bias, perm);
    acdc_main<<<dim3(NBLK), dim3(256), 0, stream>>>(x, (float*)d_out);
}